// Round 1
// baseline (139.700 us; speedup 1.0000x reference)
//
#include <hip/hip_runtime.h>

// Problem constants (reference: B,N,D,H,C = 4,512,128,128,3)
#define B_ 4
#define N_ 512
#define D_ 128
#define H_ 128
#define C_ 3
#define LDPAD 132   // 16-row tile leading dim (floats): +4 pad -> bank-conflict-free-ish

__device__ __forceinline__ float silu_f(float x) {
    // x * sigmoid(x) = x / (1 + e^{-x}); v_exp_f32 + v_rcp_f32 fast paths
    return x * __builtin_amdgcn_rcpf(1.0f + __expf(-x));
}

// A[row][h] = dot(h[row], W1[h][0:128]) + b1[h];  Bv[row][h] = dot(h[row], W1[h][128:256])
__global__ __launch_bounds__(256) void proj_kernel(
    const float* __restrict__ hd, const float* __restrict__ W1,
    const float* __restrict__ b1, float* __restrict__ A, float* __restrict__ Bv)
{
    __shared__ float hs[8 * D_];
    const int row0 = blockIdx.x * 8;
    const int tid = threadIdx.x;
    // stage 8 input rows (8*128 floats = 256 float4) cooperatively
    ((float4*)hs)[tid] = ((const float4*)(hd + row0 * D_))[tid];
    __syncthreads();

    const int hidx = tid & (H_ - 1);
    const int half = tid >> 7;  // 0 -> A (src proj), 1 -> Bv (dst proj)
    const float4* w = (const float4*)(W1 + hidx * (2 * D_) + half * D_);
    float acc[8] = {};
    #pragma unroll
    for (int d4 = 0; d4 < D_ / 4; ++d4) {
        float4 wv = w[d4];
        #pragma unroll
        for (int r = 0; r < 8; ++r) {
            float4 hv = ((const float4*)(hs + r * D_))[d4];  // uniform -> LDS broadcast
            acc[r] = fmaf(wv.x, hv.x, acc[r]);
            acc[r] = fmaf(wv.y, hv.y, acc[r]);
            acc[r] = fmaf(wv.z, hv.z, acc[r]);
            acc[r] = fmaf(wv.w, hv.w, acc[r]);
        }
    }
    const float bias = half ? 0.0f : b1[hidx];
    float* dst = half ? Bv : A;
    #pragma unroll
    for (int r = 0; r < 8; ++r)
        dst[(row0 + r) * H_ + hidx] = acc[r] + bias;   // coalesced (lanes = consecutive h)
}

// One block per (batch, upper-tri 16x16 tile pair). Each thread computes
// L[i,j] and L[j,i], averages via s = silu(pre_ij)+silu(pre_ji) BEFORE the
// W2 dot, writes out[i,j] and out[j,i].
__global__ __launch_bounds__(256) void pair_kernel(
    const float* __restrict__ A, const float* __restrict__ Bv,
    const float* __restrict__ W2, const float* __restrict__ b2,
    float* __restrict__ out)
{
    __shared__ float AI[16 * LDPAD], AJ[16 * LDPAD], BI[16 * LDPAD], BJ[16 * LDPAD];
    const int T = N_ / 16;  // 32 tiles per dim
    int tp = blockIdx.x;
    const int b = blockIdx.y;
    int I = 0;
    while (tp >= T - I) { tp -= T - I; ++I; }   // uniform scalar decode, <=32 iters
    const int J = I + tp;

    const int tid = threadIdx.x;
    const float4* sAI = (const float4*)(A  + (b * N_ + I * 16) * H_);
    const float4* sAJ = (const float4*)(A  + (b * N_ + J * 16) * H_);
    const float4* sBI = (const float4*)(Bv + (b * N_ + I * 16) * H_);
    const float4* sBJ = (const float4*)(Bv + (b * N_ + J * 16) * H_);
    #pragma unroll
    for (int k = tid; k < 512; k += 256) {      // 16 rows x 32 float4, contiguous source
        const int r = k >> 5, c = (k & 31) * 4;
        *(float4*)&AI[r * LDPAD + c] = sAI[k];
        *(float4*)&AJ[r * LDPAD + c] = sAJ[k];
        *(float4*)&BI[r * LDPAD + c] = sBI[k];
        *(float4*)&BJ[r * LDPAD + c] = sBJ[k];
    }
    __syncthreads();

    const int ti = tid >> 4, tj = tid & 15;
    const float4* w0p = (const float4*)(W2);
    const float4* w1p = (const float4*)(W2 + H_);
    const float4* w2p = (const float4*)(W2 + 2 * H_);
    float acc0 = 0.f, acc1 = 0.f, acc2 = 0.f;
    #pragma unroll 4
    for (int h4 = 0; h4 < H_ / 4; ++h4) {
        float4 ai = *(const float4*)&AI[ti * LDPAD + h4 * 4];
        float4 bj = *(const float4*)&BJ[tj * LDPAD + h4 * 4];
        float4 aj = *(const float4*)&AJ[tj * LDPAD + h4 * 4];
        float4 bi = *(const float4*)&BI[ti * LDPAD + h4 * 4];
        float4 w0 = w0p[h4], w1 = w1p[h4], w2 = w2p[h4];   // uniform -> s_load
        float s;
        s = silu_f(ai.x + bj.x) + silu_f(aj.x + bi.x);
        acc0 = fmaf(s, w0.x, acc0); acc1 = fmaf(s, w1.x, acc1); acc2 = fmaf(s, w2.x, acc2);
        s = silu_f(ai.y + bj.y) + silu_f(aj.y + bi.y);
        acc0 = fmaf(s, w0.y, acc0); acc1 = fmaf(s, w1.y, acc1); acc2 = fmaf(s, w2.y, acc2);
        s = silu_f(ai.z + bj.z) + silu_f(aj.z + bi.z);
        acc0 = fmaf(s, w0.z, acc0); acc1 = fmaf(s, w1.z, acc1); acc2 = fmaf(s, w2.z, acc2);
        s = silu_f(ai.w + bj.w) + silu_f(aj.w + bi.w);
        acc0 = fmaf(s, w0.w, acc0); acc1 = fmaf(s, w1.w, acc1); acc2 = fmaf(s, w2.w, acc2);
    }
    const float o0 = 0.5f * acc0 + b2[0];
    const float o1 = 0.5f * acc1 + b2[1];
    const float o2 = 0.5f * acc2 + b2[2];
    const int i = I * 16 + ti, j = J * 16 + tj;
    float* p1 = out + ((size_t)(b * N_ + i) * N_ + j) * C_;
    float* p2 = out + ((size_t)(b * N_ + j) * N_ + i) * C_;
    p1[0] = o0; p1[1] = o1; p1[2] = o2;
    p2[0] = o0; p2[1] = o1; p2[2] = o2;   // diagonal tiles: duplicate identical write, benign
}

extern "C" void kernel_launch(void* const* d_in, const int* in_sizes, int n_in,
                              void* d_out, int out_size, void* d_ws, size_t ws_size,
                              hipStream_t stream) {
    const float* hd = (const float*)d_in[0];
    const float* W1 = (const float*)d_in[1];
    const float* b1 = (const float*)d_in[2];
    const float* W2 = (const float*)d_in[3];
    const float* b2 = (const float*)d_in[4];
    float* out = (float*)d_out;

    float* A  = (float*)d_ws;            // [B*N][H] = 1 MiB
    float* Bv = A + B_ * N_ * H_;        // [B*N][H] = 1 MiB  (ws_size must be >= 2 MiB)

    proj_kernel<<<dim3(B_ * N_ / 8), dim3(256), 0, stream>>>(hd, W1, b1, A, Bv);

    const int T = N_ / 16;
    pair_kernel<<<dim3(T * (T + 1) / 2, B_), dim3(256), 0, stream>>>(A, Bv, W2, b2, out);
}

// Round 2
// 56.247 us; speedup vs baseline: 2.4837x; 2.4837x over previous
//
#include <hip/hip_runtime.h>

// Problem constants (reference: B,N,D,H,C = 4,512,128,128,3)
#define B_ 4
#define N_ 512
#define D_ 128
#define H_ 128
#define C_ 3
#define LDPAD 132   // pair-kernel tile leading dim (floats)

__device__ __forceinline__ float silu_f(float x) {
    // x * sigmoid(x) = x / (1 + e^{-x}); v_exp_f32 + v_rcp_f32 fast paths
    return x * __builtin_amdgcn_rcpf(1.0f + __expf(-x));
}

// C[2048][256] = h[2048][128] @ Wcat[128][256], where
//   Wcat[k][o] = W1[o & 127][(o >> 7) * 128 + k]   (o<128 -> A cols, o>=128 -> Bv cols)
// BM=BN=BK=64, 256 threads, 4x4 thread tile. Both operands transposed in LDS at
// staging time so global reads are fully-coalesced 256-B row segments.
__global__ __launch_bounds__(256) void proj_gemm(
    const float* __restrict__ hd, const float* __restrict__ W1,
    const float* __restrict__ b1, float* __restrict__ A, float* __restrict__ Bv)
{
    __shared__ float hsT[64][68];   // [k][m]  pad 68: compute reads conflict-free
    __shared__ float wt [64][68];   // [k][o]
    const int m0    = blockIdx.x * 64;
    const int by    = blockIdx.y;        // 0..3 -> output cols o0 = by*64
    const int half  = by >> 1;           // 0 -> A (W1 left half), 1 -> Bv (right half)
    const int wrow0 = (by & 1) * 64;     // W1 row base for this column tile

    const int t  = threadIdx.x;
    const int r  = t >> 4;               // 0..15 (staging row group)
    const int c4 = t & 15;               // 0..15 (staging float4 col)
    const int tx = t & 15, ty = t >> 4;  // compute: cols 4tx.., rows 4ty..

    float acc[4][4] = {};

    for (int kc = 0; kc < 2; ++kc) {
        if (kc) __syncthreads();
        // stage hsT[k][m] <- h[m0+m][kc*64 + k]  (coalesced read, LDS transpose)
        #pragma unroll
        for (int i = 0; i < 4; ++i) {
            const int m = r + 16 * i;
            float4 v = *(const float4*)&hd[(m0 + m) * D_ + kc * 64 + 4 * c4];
            hsT[4 * c4 + 0][m] = v.x; hsT[4 * c4 + 1][m] = v.y;
            hsT[4 * c4 + 2][m] = v.z; hsT[4 * c4 + 3][m] = v.w;
        }
        // stage wt[k][o] <- W1[wrow0+o][half*128 + kc*64 + k]
        #pragma unroll
        for (int i = 0; i < 4; ++i) {
            const int o = r + 16 * i;
            float4 v = *(const float4*)&W1[(wrow0 + o) * (2 * D_) + half * D_ + kc * 64 + 4 * c4];
            wt[4 * c4 + 0][o] = v.x; wt[4 * c4 + 1][o] = v.y;
            wt[4 * c4 + 2][o] = v.z; wt[4 * c4 + 3][o] = v.w;
        }
        __syncthreads();
        #pragma unroll 8
        for (int k = 0; k < 64; ++k) {
            float4 a = *(const float4*)&hsT[k][4 * ty];  // 4 addrs/wave -> broadcast
            float4 b = *(const float4*)&wt [k][4 * tx];  // 2-way -> free
            acc[0][0] = fmaf(a.x, b.x, acc[0][0]); acc[0][1] = fmaf(a.x, b.y, acc[0][1]);
            acc[0][2] = fmaf(a.x, b.z, acc[0][2]); acc[0][3] = fmaf(a.x, b.w, acc[0][3]);
            acc[1][0] = fmaf(a.y, b.x, acc[1][0]); acc[1][1] = fmaf(a.y, b.y, acc[1][1]);
            acc[1][2] = fmaf(a.y, b.z, acc[1][2]); acc[1][3] = fmaf(a.y, b.w, acc[1][3]);
            acc[2][0] = fmaf(a.z, b.x, acc[2][0]); acc[2][1] = fmaf(a.z, b.y, acc[2][1]);
            acc[2][2] = fmaf(a.z, b.z, acc[2][2]); acc[2][3] = fmaf(a.z, b.w, acc[2][3]);
            acc[3][0] = fmaf(a.w, b.x, acc[3][0]); acc[3][1] = fmaf(a.w, b.y, acc[3][1]);
            acc[3][2] = fmaf(a.w, b.z, acc[3][2]); acc[3][3] = fmaf(a.w, b.w, acc[3][3]);
        }
    }

    // epilogue: add bias (A side only), write coalesced float4
    float* dst = half ? Bv : A;
    const int ocol = wrow0 + 4 * tx;          // column within the 128-wide A/Bv
    float4 bias = make_float4(0.f, 0.f, 0.f, 0.f);
    if (!half) bias = *(const float4*)&b1[ocol];
    #pragma unroll
    for (int i = 0; i < 4; ++i) {
        float4 o;
        o.x = acc[i][0] + bias.x; o.y = acc[i][1] + bias.y;
        o.z = acc[i][2] + bias.z; o.w = acc[i][3] + bias.w;
        *(float4*)&dst[(m0 + 4 * ty + i) * H_ + ocol] = o;
    }
}

// One block per (batch, upper-tri 16x16 tile pair). Each thread computes
// L[i,j] and L[j,i], averages via s = silu(pre_ij)+silu(pre_ji) BEFORE the
// W2 dot, writes out[i,j] and out[j,i].
__global__ __launch_bounds__(256) void pair_kernel(
    const float* __restrict__ A, const float* __restrict__ Bv,
    const float* __restrict__ W2, const float* __restrict__ b2,
    float* __restrict__ out)
{
    __shared__ float AI[16 * LDPAD], AJ[16 * LDPAD], BI[16 * LDPAD], BJ[16 * LDPAD];
    const int T = N_ / 16;  // 32 tiles per dim
    int tp = blockIdx.x;
    const int b = blockIdx.y;
    int I = 0;
    while (tp >= T - I) { tp -= T - I; ++I; }   // uniform scalar decode, <=32 iters
    const int J = I + tp;

    const int tid = threadIdx.x;
    const float4* sAI = (const float4*)(A  + (b * N_ + I * 16) * H_);
    const float4* sAJ = (const float4*)(A  + (b * N_ + J * 16) * H_);
    const float4* sBI = (const float4*)(Bv + (b * N_ + I * 16) * H_);
    const float4* sBJ = (const float4*)(Bv + (b * N_ + J * 16) * H_);
    #pragma unroll
    for (int k = tid; k < 512; k += 256) {      // 16 rows x 32 float4, contiguous source
        const int r = k >> 5, c = (k & 31) * 4;
        *(float4*)&AI[r * LDPAD + c] = sAI[k];
        *(float4*)&AJ[r * LDPAD + c] = sAJ[k];
        *(float4*)&BI[r * LDPAD + c] = sBI[k];
        *(float4*)&BJ[r * LDPAD + c] = sBJ[k];
    }
    __syncthreads();

    const int ti = tid >> 4, tj = tid & 15;
    const float4* w0p = (const float4*)(W2);
    const float4* w1p = (const float4*)(W2 + H_);
    const float4* w2p = (const float4*)(W2 + 2 * H_);
    float acc0 = 0.f, acc1 = 0.f, acc2 = 0.f;
    #pragma unroll 4
    for (int h4 = 0; h4 < H_ / 4; ++h4) {
        float4 ai = *(const float4*)&AI[ti * LDPAD + h4 * 4];
        float4 bj = *(const float4*)&BJ[tj * LDPAD + h4 * 4];
        float4 aj = *(const float4*)&AJ[tj * LDPAD + h4 * 4];
        float4 bi = *(const float4*)&BI[ti * LDPAD + h4 * 4];
        float4 w0 = w0p[h4], w1 = w1p[h4], w2 = w2p[h4];   // uniform -> s_load
        float s;
        s = silu_f(ai.x + bj.x) + silu_f(aj.x + bi.x);
        acc0 = fmaf(s, w0.x, acc0); acc1 = fmaf(s, w1.x, acc1); acc2 = fmaf(s, w2.x, acc2);
        s = silu_f(ai.y + bj.y) + silu_f(aj.y + bi.y);
        acc0 = fmaf(s, w0.y, acc0); acc1 = fmaf(s, w1.y, acc1); acc2 = fmaf(s, w2.y, acc2);
        s = silu_f(ai.z + bj.z) + silu_f(aj.z + bi.z);
        acc0 = fmaf(s, w0.z, acc0); acc1 = fmaf(s, w1.z, acc1); acc2 = fmaf(s, w2.z, acc2);
        s = silu_f(ai.w + bj.w) + silu_f(aj.w + bi.w);
        acc0 = fmaf(s, w0.w, acc0); acc1 = fmaf(s, w1.w, acc1); acc2 = fmaf(s, w2.w, acc2);
    }
    const float o0 = 0.5f * acc0 + b2[0];
    const float o1 = 0.5f * acc1 + b2[1];
    const float o2 = 0.5f * acc2 + b2[2];
    const int i = I * 16 + ti, j = J * 16 + tj;
    float* p1 = out + ((size_t)(b * N_ + i) * N_ + j) * C_;
    float* p2 = out + ((size_t)(b * N_ + j) * N_ + i) * C_;
    p1[0] = o0; p1[1] = o1; p1[2] = o2;
    p2[0] = o0; p2[1] = o1; p2[2] = o2;   // diagonal tiles: duplicate identical write, benign
}

extern "C" void kernel_launch(void* const* d_in, const int* in_sizes, int n_in,
                              void* d_out, int out_size, void* d_ws, size_t ws_size,
                              hipStream_t stream) {
    const float* hd = (const float*)d_in[0];
    const float* W1 = (const float*)d_in[1];
    const float* b1 = (const float*)d_in[2];
    const float* W2 = (const float*)d_in[3];
    const float* b2 = (const float*)d_in[4];
    float* out = (float*)d_out;

    float* A  = (float*)d_ws;            // [B*N][H] = 1 MiB
    float* Bv = A + B_ * N_ * H_;        // [B*N][H] = 1 MiB  (ws_size must be >= 2 MiB)

    proj_gemm<<<dim3((B_ * N_) / 64, 4), dim3(256), 0, stream>>>(hd, W1, b1, A, Bv);

    const int T = N_ / 16;
    pair_kernel<<<dim3(T * (T + 1) / 2, B_), dim3(256), 0, stream>>>(A, Bv, W2, b2, out);
}

// Round 4
// 50.559 us; speedup vs baseline: 2.7631x; 1.1125x over previous
//
#include <hip/hip_runtime.h>

// Problem constants (reference: B,N,D,H,C = 4,512,128,128,3)
#define B_ 4
#define N_ 512
#define D_ 128
#define H_ 128
#define C_ 3
#define LDPAD 132   // pair-kernel tile leading dim (floats)

#define NEG_LOG2E   (-1.4426950408889634f)
#define NEG_HALF_LN2 (-0.34657359027997264f)   // -0.5 * ln(2)

__device__ __forceinline__ float exp2_fast(float x) {
    return __builtin_amdgcn_exp2f(x);   // raw v_exp_f32 (2^x)
}

// Projections are stored PRE-SCALED by -log2e:
//   At[row][h] = -log2e * (dot(h[row], W1[h][0:128]) + b1[h])
//   Bt[row][h] = -log2e *  dot(h[row], W1[h][128:256])
// so the pair kernel computes, with y = At_i + Bt_j  (= -pre * log2e):
//   e^{-pre} = 2^y  (single v_exp_f32),  silu(pre) = -ln2 * y / (1 + 2^y)
// and -0.5*ln2 (silu scale * symmetrize) is folded into the final accumulators.
__global__ __launch_bounds__(256) void proj_gemm(
    const float* __restrict__ hd, const float* __restrict__ W1,
    const float* __restrict__ b1, float* __restrict__ At, float* __restrict__ Bt)
{
    __shared__ float hsT[64][68];   // [k][m]
    __shared__ float wt [64][68];   // [k][o]
    const int m0    = blockIdx.x * 64;
    const int by    = blockIdx.y;        // 0..3 -> output cols o0 = by*64
    const int half  = by >> 1;           // 0 -> At (W1 left half), 1 -> Bt (right half)
    const int wrow0 = (by & 1) * 64;     // W1 row base for this column tile

    const int t  = threadIdx.x;
    const int r  = t >> 4;               // 0..15 (staging row group)
    const int c4 = t & 15;               // 0..15 (staging float4 col)
    const int tx = t & 15, ty = t >> 4;  // compute: cols 4tx.., rows 4ty..

    float acc[4][4] = {};

    for (int kc = 0; kc < 2; ++kc) {
        if (kc) __syncthreads();
        #pragma unroll
        for (int i = 0; i < 4; ++i) {
            const int m = r + 16 * i;
            float4 v = *(const float4*)&hd[(m0 + m) * D_ + kc * 64 + 4 * c4];
            hsT[4 * c4 + 0][m] = v.x; hsT[4 * c4 + 1][m] = v.y;
            hsT[4 * c4 + 2][m] = v.z; hsT[4 * c4 + 3][m] = v.w;
        }
        #pragma unroll
        for (int i = 0; i < 4; ++i) {
            const int o = r + 16 * i;
            float4 v = *(const float4*)&W1[(wrow0 + o) * (2 * D_) + half * D_ + kc * 64 + 4 * c4];
            wt[4 * c4 + 0][o] = v.x; wt[4 * c4 + 1][o] = v.y;
            wt[4 * c4 + 2][o] = v.z; wt[4 * c4 + 3][o] = v.w;
        }
        __syncthreads();
        #pragma unroll 8
        for (int k = 0; k < 64; ++k) {
            float4 a = *(const float4*)&hsT[k][4 * ty];
            float4 b = *(const float4*)&wt [k][4 * tx];
            acc[0][0] = fmaf(a.x, b.x, acc[0][0]); acc[0][1] = fmaf(a.x, b.y, acc[0][1]);
            acc[0][2] = fmaf(a.x, b.z, acc[0][2]); acc[0][3] = fmaf(a.x, b.w, acc[0][3]);
            acc[1][0] = fmaf(a.y, b.x, acc[1][0]); acc[1][1] = fmaf(a.y, b.y, acc[1][1]);
            acc[1][2] = fmaf(a.y, b.z, acc[1][2]); acc[1][3] = fmaf(a.y, b.w, acc[1][3]);
            acc[2][0] = fmaf(a.z, b.x, acc[2][0]); acc[2][1] = fmaf(a.z, b.y, acc[2][1]);
            acc[2][2] = fmaf(a.z, b.z, acc[2][2]); acc[2][3] = fmaf(a.z, b.w, acc[2][3]);
            acc[3][0] = fmaf(a.w, b.x, acc[3][0]); acc[3][1] = fmaf(a.w, b.y, acc[3][1]);
            acc[3][2] = fmaf(a.w, b.z, acc[3][2]); acc[3][3] = fmaf(a.w, b.w, acc[3][3]);
        }
    }

    float* dst = half ? Bt : At;
    const int ocol = wrow0 + 4 * tx;
    float4 bias = make_float4(0.f, 0.f, 0.f, 0.f);
    if (!half) bias = *(const float4*)&b1[ocol];
    #pragma unroll
    for (int i = 0; i < 4; ++i) {
        float4 o;
        o.x = (acc[i][0] + bias.x) * NEG_LOG2E;
        o.y = (acc[i][1] + bias.y) * NEG_LOG2E;
        o.z = (acc[i][2] + bias.z) * NEG_LOG2E;
        o.w = (acc[i][3] + bias.w) * NEG_LOG2E;
        *(float4*)&dst[(m0 + 4 * ty + i) * H_ + ocol] = o;
    }
}

// One block per (batch, upper-tri 16x16 tile pair). Per (pair,h):
//   y1 = At_i + Bt_j, y2 = At_j + Bt_i          (2 add)
//   e1 = 2^y1, e2 = 2^y2                        (2 v_exp)
//   d1 = 1+e1, d2 = 1+e2                        (2 add)
//   r  = rcp(d1*d2)                             (1 mul + 1 v_rcp, shared)
//   s  = (y1*d2 + y2*d1) * r                    (1 mul + 1 fma + 1 mul)
//   acc_c += s * W2[c][h]                       (3 fma)
// epilogue: out_c = NEG_HALF_LN2 * acc_c + b2[c]
__global__ __launch_bounds__(256, 4) void pair_kernel(
    const float* __restrict__ At, const float* __restrict__ Bt,
    const float* __restrict__ W2, const float* __restrict__ b2,
    float* __restrict__ out)
{
    __shared__ float AI[16 * LDPAD], AJ[16 * LDPAD], BI[16 * LDPAD], BJ[16 * LDPAD];
    const int T = N_ / 16;  // 32 tiles per dim
    int tp = blockIdx.x;
    const int b = blockIdx.y;
    int I = 0;
    while (tp >= T - I) { tp -= T - I; ++I; }   // uniform scalar decode
    const int J = I + tp;

    const int tid = threadIdx.x;
    const float4* sAI = (const float4*)(At + (b * N_ + I * 16) * H_);
    const float4* sAJ = (const float4*)(At + (b * N_ + J * 16) * H_);
    const float4* sBI = (const float4*)(Bt + (b * N_ + I * 16) * H_);
    const float4* sBJ = (const float4*)(Bt + (b * N_ + J * 16) * H_);
    #pragma unroll
    for (int k = tid; k < 512; k += 256) {
        const int r = k >> 5, c = (k & 31) * 4;
        *(float4*)&AI[r * LDPAD + c] = sAI[k];
        *(float4*)&AJ[r * LDPAD + c] = sAJ[k];
        *(float4*)&BI[r * LDPAD + c] = sBI[k];
        *(float4*)&BJ[r * LDPAD + c] = sBJ[k];
    }
    __syncthreads();

    const int ti = tid >> 4, tj = tid & 15;
    const float4* w0p = (const float4*)(W2);
    const float4* w1p = (const float4*)(W2 + H_);
    const float4* w2p = (const float4*)(W2 + 2 * H_);
    float acc0 = 0.f, acc1 = 0.f, acc2 = 0.f;
    #pragma unroll 4
    for (int h4 = 0; h4 < H_ / 4; ++h4) {
        float4 ai = *(const float4*)&AI[ti * LDPAD + h4 * 4];
        float4 bj = *(const float4*)&BJ[tj * LDPAD + h4 * 4];
        float4 aj = *(const float4*)&AJ[tj * LDPAD + h4 * 4];
        float4 bi = *(const float4*)&BI[ti * LDPAD + h4 * 4];
        float4 w0 = w0p[h4], w1 = w1p[h4], w2 = w2p[h4];   // uniform -> s_load

        #define PAIR_H(comp)                                                      \
        {                                                                         \
            const float y1 = ai.comp + bj.comp;                                   \
            const float y2 = aj.comp + bi.comp;                                   \
            const float e1 = exp2_fast(y1);                                       \
            const float e2 = exp2_fast(y2);                                       \
            const float d1 = 1.0f + e1;                                           \
            const float d2 = 1.0f + e2;                                           \
            const float r  = __builtin_amdgcn_rcpf(d1 * d2);                      \
            const float s  = fmaf(y2, d1, y1 * d2) * r;                           \
            acc0 = fmaf(s, w0.comp, acc0);                                        \
            acc1 = fmaf(s, w1.comp, acc1);                                        \
            acc2 = fmaf(s, w2.comp, acc2);                                        \
        }
        PAIR_H(x) PAIR_H(y) PAIR_H(z) PAIR_H(w)
        #undef PAIR_H
    }
    const float o0 = fmaf(NEG_HALF_LN2, acc0, b2[0]);
    const float o1 = fmaf(NEG_HALF_LN2, acc1, b2[1]);
    const float o2 = fmaf(NEG_HALF_LN2, acc2, b2[2]);
    const int i = I * 16 + ti, j = J * 16 + tj;
    float* p1 = out + ((size_t)(b * N_ + i) * N_ + j) * C_;
    float* p2 = out + ((size_t)(b * N_ + j) * N_ + i) * C_;
    p1[0] = o0; p1[1] = o1; p1[2] = o2;
    p2[0] = o0; p2[1] = o1; p2[2] = o2;
}

extern "C" void kernel_launch(void* const* d_in, const int* in_sizes, int n_in,
                              void* d_out, int out_size, void* d_ws, size_t ws_size,
                              hipStream_t stream) {
    const float* hd = (const float*)d_in[0];
    const float* W1 = (const float*)d_in[1];
    const float* b1 = (const float*)d_in[2];
    const float* W2 = (const float*)d_in[3];
    const float* b2 = (const float*)d_in[4];
    float* out = (float*)d_out;

    float* At = (float*)d_ws;            // [B*N][H] = 1 MiB (scaled by -log2e)
    float* Bt = At + B_ * N_ * H_;       // [B*N][H] = 1 MiB

    proj_gemm<<<dim3((B_ * N_) / 64, 4), dim3(256), 0, stream>>>(hd, W1, b1, At, Bt);

    const int T = N_ / 16;
    pair_kernel<<<dim3(T * (T + 1) / 2, B_), dim3(256), 0, stream>>>(At, Bt, W2, b2, out);
}